// Round 4
// baseline (634.564 us; speedup 1.0000x reference)
//
#include <hip/hip_runtime.h>

// ---------------------------------------------------------------------------
// MultiDimensionalLSTM on MI355X.
// B=32, C=32, Y=X=128, win 4x4 -> grid 32x32 cells, F=512, R=128, gates 5R=640.
// Input projection hoisted to one split-bf16 MFMA GEMM.
//
// R9: R8 post-mortem: merging two poll RTs into one saved only 5% -> each
// "RT" is ~5us, i.e. the data-as-flag SPIN TRAFFIC congests the MALL
// (~45KB/block/retry, ~12 TB/s of scattered 64B-line reads). Fix: per-block
// progress FLAGS with near-zero poll footprint.
//   producer: data stores (relaxed sc1) -> s_waitcnt vmcnt(0) + __syncthreads
//             (all data COMPLETE at MALL) -> tid0 RELAXED sc1 flag store.
//             Ordering is by construction (flag issued only after data
//             completion), so no release/wbl2 needed. R4's stale-read failure
//             had no drain between data and flag; this does.
//   consumer: polls <=3 u32 flags (same addr across lanes -> 1 coalesced
//             request/wave/retry, ~500x less poll traffic), then loads the
//             remote data ONCE; its single RT hides under phase-A MFMAs.
// Everything else unchanged from R8 (verified): gate-major weight tiles in
// registers (4 waves = 1 wave/SIMD = 512-reg budget), own-left via LDS
// double buffer, in-register epilogue, one barrier/step.
// ---------------------------------------------------------------------------

typedef unsigned short u16;
typedef unsigned int u32;
typedef unsigned long long u64;
typedef __attribute__((ext_vector_type(8))) short short8;     // 8 bf16 (4 VGPRs)
typedef __attribute__((ext_vector_type(8))) unsigned short us8;
typedef __attribute__((ext_vector_type(4))) float floatx4;

__device__ inline u16 f2bf(float f) {               // RNE fp32 -> bf16
  unsigned u = __float_as_uint(f);
  u += 0x7fffu + ((u >> 16) & 1u);
  return (u16)(u >> 16);
}
__device__ inline float bf2f(u16 v) { return __uint_as_float(((unsigned)v) << 16); }

__device__ inline void async16(u16* lds, const u16* g) {
  __builtin_amdgcn_global_load_lds((const __attribute__((address_space(1))) void*)g,
                                   (__attribute__((address_space(3))) void*)lds, 16, 0, 0);
}

__device__ inline float sigf(float x) { return 1.f / (1.f + __expf(-x)); }
__device__ inline float tanh_fast(float x) { return 1.f - 2.f / (__expf(2.f * x) + 1.f); }

// Relaxed agent-scope primitives: sc1 loads/stores straight to the MALL.
__device__ inline u32 aload32(const u32* p) {
  return __hip_atomic_load(p, __ATOMIC_RELAXED, __HIP_MEMORY_SCOPE_AGENT);
}
__device__ inline u64 aload64(const u64* p) {
  return __hip_atomic_load(p, __ATOMIC_RELAXED, __HIP_MEMORY_SCOPE_AGENT);
}
__device__ inline void astore32(u32* p, u32 v) {
  __hip_atomic_store(p, v, __ATOMIC_RELAXED, __HIP_MEMORY_SCOPE_AGENT);
}
__device__ inline void astore64(u64* p, u64 v) {
  __hip_atomic_store(p, v, __ATOMIC_RELAXED, __HIP_MEMORY_SCOPE_AGENT);
}
// split 4 u64 of packed (hi | lo<<16) words into hi-plane / lo-plane bf16x8
__device__ inline void unpack8(const u64 q[4], short8* H, short8* L) {
  union { u32 w[4]; short8 s; } uh, ul;
#pragma unroll
  for (int i = 0; i < 4; ++i) {
    u32 a = (u32)q[i], b = (u32)(q[i] >> 32);
    uh.w[i] = (a & 0xFFFFu) | (b << 16);
    ul.w[i] = (a >> 16) | (b & 0xFFFF0000u);
  }
  *H = uh.s; *L = ul.s;
}

// ---------------------------------------------------------------------------
// Prep 1: W [768][640] fp32 -> WxT_{h,l} [640 pcol][512 k] (pcol = r*5+g,
// gate-interleaved for the input GEMM), WhT_{h,l} [640 col][256 k] in ORIGINAL
// column order (col = g*128 + r; k_rec retiles gate-major), biasp [640 pcol].
// ---------------------------------------------------------------------------
__global__ __launch_bounds__(256) void k_wprep(const float* __restrict__ W,
                                               const float* __restrict__ bias,
                                               u16* __restrict__ WxT_h, u16* __restrict__ WxT_l,
                                               u16* __restrict__ WhT_h, u16* __restrict__ WhT_l,
                                               float* __restrict__ biasp) {
  int pcol = blockIdx.x;                       // 0..639
  int col  = (pcol % 5) * 128 + pcol / 5;      // original gate column
  for (int k = threadIdx.x; k < 768; k += 256) {
    float v = W[(size_t)k * 640 + col];
    u16 hi = f2bf(v);
    u16 lo = f2bf(v - bf2f(hi));
    if (k < 512) { WxT_h[(size_t)pcol * 512 + k] = hi; WxT_l[(size_t)pcol * 512 + k] = lo; }
    else { WhT_h[(size_t)col * 256 + (k - 512)] = hi; WhT_l[(size_t)col * 256 + (k - 512)] = lo; }
  }
  if (threadIdx.x == 0) biasp[pcol] = bias[col];
}

// ---------------------------------------------------------------------------
// Prep 2: gather x [B,C,Y,X] -> xs hi/lo [t][b][f].
// xs[t][b][f] = x[b][f&31][t>>3][(t&7)*16 + (f>>5)]
// ---------------------------------------------------------------------------
__global__ __launch_bounds__(256) void k_xgather(const float* __restrict__ x,
                                                 u16* __restrict__ xs_h,
                                                 u16* __restrict__ xs_l) {
  int lane = threadIdx.x & 63;
  int pair = blockIdx.x * 4 + (threadIdx.x >> 6);  // t*32+b
  int t = pair >> 5, b = pair & 31;
  int y = t >> 3, x0 = (t & 7) * 16;
  int j = lane >> 2;
  int cbase = (lane & 3) * 8;
  const float* src = x + ((size_t)b * 32 * 128 + y) * 128 + x0 + j;
  us8 vh, vl;
#pragma unroll
  for (int u = 0; u < 8; ++u) {
    float f = src[(size_t)(cbase + u) * 16384];
    u16 hi = f2bf(f);
    vh[u] = hi;
    vl[u] = f2bf(f - bf2f(hi));
  }
  *(us8*)(xs_h + (size_t)pair * 512 + lane * 8) = vh;
  *(us8*)(xs_l + (size_t)pair * 512 + lane * 8) = vl;
}

// ---------------------------------------------------------------------------
// Input GEMM (split-bf16): M=32768, N=640, K=512. 128x128 tile, BK=32.
// Epilogue stores Gp in [t][pcol][32 b] layout (16B aligned floatx4).
// ---------------------------------------------------------------------------
__global__ __launch_bounds__(256) void k_gemm_in(const u16* __restrict__ xs_h,
                                                 const u16* __restrict__ xs_l,
                                                 const u16* __restrict__ WxT_h,
                                                 const u16* __restrict__ WxT_l,
                                                 const float* __restrict__ biasp,
                                                 float* __restrict__ Gp) {
  __shared__ u16 Ah[128 * 32], Al[128 * 32];
  __shared__ u16 Bh[128 * 32], Bl[128 * 32];
  const int tid = threadIdx.x;
  const int wv = tid >> 6, lane = tid & 63;
  const int quad = lane >> 4, l16 = lane & 15;
  const int m0 = blockIdx.x * 128;
  const int n0 = blockIdx.y * 128;
  const int arow = lane >> 2;
  const int acol = (lane & 3) * 8;

  floatx4 acc[4][4] = {};

  for (int kt = 0; kt < 512; kt += 32) {
#pragma unroll
    for (int i = 0; i < 2; ++i) {
      int chunk = wv * 2 + i;
      int row = chunk * 16 + arow;
      size_t aoff = (size_t)(m0 + row) * 512 + kt + acol;
      size_t boff = (size_t)(n0 + row) * 512 + kt + acol;
      async16(&Ah[chunk * 512 + lane * 8], xs_h + aoff);
      async16(&Al[chunk * 512 + lane * 8], xs_l + aoff);
      async16(&Bh[chunk * 512 + lane * 8], WxT_h + boff);
      async16(&Bl[chunk * 512 + lane * 8], WxT_l + boff);
    }
    __syncthreads();
    short8 afh[4], afl[4], bfh[4], bfl[4];
#pragma unroll
    for (int mt = 0; mt < 4; ++mt) {
      int ro = ((wv & 1) * 64 + mt * 16 + l16) * 32 + quad * 8;
      afh[mt] = *(const short8*)&Ah[ro];
      afl[mt] = *(const short8*)&Al[ro];
    }
#pragma unroll
    for (int nt = 0; nt < 4; ++nt) {
      int ro = ((wv >> 1) * 64 + nt * 16 + l16) * 32 + quad * 8;
      bfh[nt] = *(const short8*)&Bh[ro];
      bfl[nt] = *(const short8*)&Bl[ro];
    }
#pragma unroll
    for (int mt = 0; mt < 4; ++mt)
#pragma unroll
      for (int nt = 0; nt < 4; ++nt) {
        floatx4 a = acc[mt][nt];
        a = __builtin_amdgcn_mfma_f32_16x16x32_bf16(afl[mt], bfh[nt], a, 0, 0, 0);
        a = __builtin_amdgcn_mfma_f32_16x16x32_bf16(afh[mt], bfl[nt], a, 0, 0, 0);
        a = __builtin_amdgcn_mfma_f32_16x16x32_bf16(afh[mt], bfh[nt], a, 0, 0, 0);
        acc[mt][nt] = a;
      }
    __syncthreads();
  }
#pragma unroll
  for (int nt = 0; nt < 4; ++nt) {
    int n = n0 + (wv >> 1) * 64 + nt * 16 + l16;
    float bv = biasp[n];
#pragma unroll
    for (int mt = 0; mt < 4; ++mt) {
      int mBase = m0 + (wv & 1) * 64 + mt * 16 + quad * 4;   // 4 consecutive m, same t
      int tt = mBase >> 5, bb = mBase & 31;
      floatx4 vv;
#pragma unroll
      for (int r = 0; r < 4; ++r) vv[r] = acc[mt][nt][r] + bv;
      *(floatx4*)&Gp[((size_t)tt * 640 + n) * 32 + bb] = vv;
    }
  }
}

// ---------------------------------------------------------------------------
// Persistent recurrence. Grid 128: bid = h*4 + s*2 + hf (lower h first).
// Block 256 thr = 4 waves = 1 wave/SIMD (512-reg unified budget).
// Block (s,hf,h): batches sb..sb+16, r in [hf*64, hf*64+64).
// flags[s*64 + hf*32 + h] = steps completed by that block (data at MALL).
// Step w deps: up (t>32): flags[s,0,h-1] > w AND flags[s,1,h-1] > w;
//              left (w>0): flags[s,1-hf,h] >= w.
// ---------------------------------------------------------------------------
__global__ __launch_bounds__(256, 1) void k_rec(const u16* __restrict__ WhT_h,
                                                const u16* __restrict__ WhT_l,
                                                const float* __restrict__ Gp,
                                                u64* __restrict__ cbuf,   // f32 [t][128 r][32 b]
                                                u32* __restrict__ hb,     // [t*32+b][128 r] hi|lo<<16
                                                float* __restrict__ out,
                                                u32* __restrict__ flags) {
  __shared__ u16 h2h[2][1024], h2l[2][1024];   // [buf][16 b][64 r], XOR-swizzled

  const int hf = blockIdx.x & 1;
  const int s  = (blockIdx.x >> 1) & 1;
  const int h  = blockIdx.x >> 2;
  const int sb = s * 16;
  const int tid = threadIdx.x;
  const int wv = tid >> 6, lane = tid & 63;
  const int quad = lane >> 4, l16 = lane & 15;
  const int r0 = hf * 64 + wv * 16;
  const int rg = r0 + l16;                     // this lane's r
  const int b0 = sb + quad * 4;                // this lane's batch base
  const int hm1 = (h > 0) ? h - 1 : 0;
  const u32* fu0 = flags + s * 64 + hm1;            // up, hf=0
  const u32* fu1 = flags + s * 64 + 32 + hm1;       // up, hf=1
  const u32* fsb = flags + s * 64 + (1 - hf) * 32 + h;  // sibling
  u32* fme = flags + s * 64 + hf * 32 + h;

  // ---- Wh fragments -> registers, once. Static reg indexing; ks slots:
  // 0..3 = up (k 0..127); 4..5 = OWN left half (k 128+hf*64+..); 6..7 = SIB.
  short8 Bw_h[5][8], Bw_l[5][8];
#pragma unroll
  for (int g = 0; g < 5; ++g) {
    const u16* ph = WhT_h + (size_t)(g * 128 + rg) * 256 + quad * 8;
    const u16* pl = WhT_l + (size_t)(g * 128 + rg) * 256 + quad * 8;
#pragma unroll
    for (int ks = 0; ks < 8; ++ks) {
      int kk;
      if (ks < 4)      kk = ks * 32;
      else if (ks < 6) kk = 128 + hf * 64 + (ks - 4) * 32;
      else             kk = 128 + (1 - hf) * 64 + (ks - 6) * 32;
      Bw_h[g][ks] = *(const short8*)(ph + kk);
      Bw_l[g][ks] = *(const short8*)(pl + kk);
    }
  }

  float cl[4] = {0.f, 0.f, 0.f, 0.f};          // c_left, this lane's 4 cells

  for (int w = 0; w < 32; ++w) {
    const int t = h * 32 + w;
    const bool upok = t > 32;                  // faithful off-by-one
    const bool leftok = w > 0;

    // gate biases from Gp (plain cached loads; in flight during the wait)
    floatx4 gg[5];
    {
      const float* gpb = Gp + ((size_t)t * 640 + rg * 5) * 32 + b0;
#pragma unroll
      for (int g = 0; g < 5; ++g) gg[g] = *(const floatx4*)(gpb + g * 32);
    }

    // ---- flag wait: <=3 u32 loads per retry (coalesced across lanes) ----
    if (upok | (int)leftok) {
      for (;;) {
        u32 ok = 1u;
        if (upok)   ok &= (aload32(fu0) > (u32)w) & (aload32(fu1) > (u32)w);
        if (leftok) ok &= (aload32(fsb) >= (u32)w);
        if (ok) break;
        __builtin_amdgcn_s_sleep(1);
        __asm__ __volatile__("" ::: "memory");
      }
      __asm__ __volatile__("" ::: "memory");
    }

    // ---- issue remote data loads ONCE (flag proved completion at MALL) ----
    u64 uq[4][4]; u64 sq[2][4]; u64 cq0 = 0, cq1 = 0;
    const u64* hb64 = (const u64*)hb;
    const int sk0 = (1 - hf) * 2;
    if (upok) {
      size_t ub = (((size_t)(t - 32) * 32 + sb + l16) * 128 + quad * 8) >> 1;
      size_t cb = (((size_t)(t - 32) * 128 + rg) * 32 + b0) >> 1;
#pragma unroll
      for (int ks = 0; ks < 4; ++ks)
#pragma unroll
        for (int i = 0; i < 4; ++i) uq[ks][i] = aload64(hb64 + ub + ks * 16 + i);
      cq0 = aload64(cbuf + cb); cq1 = aload64(cbuf + cb + 1);
    }
    if (leftok) {
      size_t sbase = (((size_t)(t - 1) * 32 + sb + l16) * 128 + quad * 8) >> 1;
#pragma unroll
      for (int j = 0; j < 2; ++j)
#pragma unroll
        for (int i = 0; i < 4; ++i) sq[j][i] = aload64(hb64 + sbase + (sk0 + j) * 16 + i);
    }

    floatx4 acc[5] = {};

    // ---- phase A: own-left MFMAs from LDS (hide the remote-load RT) ----
    if (leftok) {
      const int bsel = (w - 1) & 1;
#pragma unroll
      for (int j = 0; j < 2; ++j) {
        int idx = (l16 * 64 + j * 32 + quad * 8) ^ ((l16 & 7) << 3);
        short8 ah = *(const short8*)&h2h[bsel][idx];
        short8 al = *(const short8*)&h2l[bsel][idx];
#pragma unroll
        for (int g = 0; g < 5; ++g) {
          floatx4 a = acc[g];
          a = __builtin_amdgcn_mfma_f32_16x16x32_bf16(al, Bw_h[g][4 + j], a, 0, 0, 0);
          a = __builtin_amdgcn_mfma_f32_16x16x32_bf16(ah, Bw_l[g][4 + j], a, 0, 0, 0);
          a = __builtin_amdgcn_mfma_f32_16x16x32_bf16(ah, Bw_h[g][4 + j], a, 0, 0, 0);
          acc[g] = a;
        }
      }
    }

    // ---- phase B: remote-dep MFMAs (compiler inserts vmcnt waits on use) ----
    if (upok) {
#pragma unroll
      for (int ks = 0; ks < 4; ++ks) {
        short8 ah, al;
        unpack8(uq[ks], &ah, &al);
#pragma unroll
        for (int g = 0; g < 5; ++g) {
          floatx4 a = acc[g];
          a = __builtin_amdgcn_mfma_f32_16x16x32_bf16(al, Bw_h[g][ks], a, 0, 0, 0);
          a = __builtin_amdgcn_mfma_f32_16x16x32_bf16(ah, Bw_l[g][ks], a, 0, 0, 0);
          a = __builtin_amdgcn_mfma_f32_16x16x32_bf16(ah, Bw_h[g][ks], a, 0, 0, 0);
          acc[g] = a;
        }
      }
    }
    if (leftok) {
#pragma unroll
      for (int j = 0; j < 2; ++j) {
        short8 ah, al;
        unpack8(sq[j], &ah, &al);
#pragma unroll
        for (int g = 0; g < 5; ++g) {
          floatx4 a = acc[g];
          a = __builtin_amdgcn_mfma_f32_16x16x32_bf16(al, Bw_h[g][6 + j], a, 0, 0, 0);
          a = __builtin_amdgcn_mfma_f32_16x16x32_bf16(ah, Bw_l[g][6 + j], a, 0, 0, 0);
          a = __builtin_amdgcn_mfma_f32_16x16x32_bf16(ah, Bw_h[g][6 + j], a, 0, 0, 0);
          acc[g] = a;
        }
      }
    }

    // ---- in-register epilogue: lane's 4 cells (b0+u, rg) ----
    float c1v[4];
    c1v[0] = __uint_as_float((u32)cq0); c1v[1] = __uint_as_float((u32)(cq0 >> 32));
    c1v[2] = __uint_as_float((u32)cq1); c1v[3] = __uint_as_float((u32)(cq1 >> 32));
    float nh[4]; u32 hpack[4];
#pragma unroll
    for (int u = 0; u < 4; ++u) {
      float gi = acc[0][u] + gg[0][u];
      float gj = acc[1][u] + gg[1][u];
      float ga = acc[2][u] + gg[2][u];
      float gb = acc[3][u] + gg[3][u];
      float go = acc[4][u] + gg[4][u];
      float c1 = upok ? c1v[u] : 0.f;
      float c2 = leftok ? cl[u] : 0.f;
      float nc = c1 * sigf(ga) + c2 * sigf(gb) + sigf(gi) * tanh_fast(gj);
      float nhv = tanh_fast(nc) * sigf(go);
      cl[u] = nc;
      nh[u] = nhv;
      u16 hi = f2bf(nhv);
      u16 lo = f2bf(nhv - bf2f(hi));
      hpack[u] = (u32)hi | ((u32)lo << 16);
    }
    // global publication (relaxed sc1)
    const size_t hbase = ((size_t)t * 32 + b0) * 128 + rg;
#pragma unroll
    for (int u = 0; u < 4; ++u) astore32(hb + hbase + (size_t)u * 128, hpack[u]);
    const size_t cw = (((size_t)t * 128 + rg) * 32 + b0) >> 1;
    astore64(cbuf + cw,     (u64)__float_as_uint(cl[0]) | ((u64)__float_as_uint(cl[1]) << 32));
    astore64(cbuf + cw + 1, (u64)__float_as_uint(cl[2]) | ((u64)__float_as_uint(cl[3]) << 32));
#pragma unroll
    for (int u = 0; u < 4; ++u)
      out[(((size_t)(b0 + u) * 32 + h) * 32 + w) * 128 + rg] = nh[u];
    // own-half h -> LDS for next step's phase A
    {
      const int bsel = w & 1;
#pragma unroll
      for (int u = 0; u < 4; ++u) {
        int bl = quad * 4 + u;
        int idx = (bl * 64 + wv * 16 + l16) ^ ((bl & 7) << 3);
        h2h[bsel][idx] = (u16)(hpack[u] & 0xFFFFu);
        h2l[bsel][idx] = (u16)(hpack[u] >> 16);
      }
    }
    // All sc1 data stores COMPLETE (at the MALL) before the barrier releases;
    // flag store is issued strictly after -> cannot be visible before data.
    __asm__ __volatile__("s_waitcnt vmcnt(0)" ::: "memory");
    __syncthreads();
    if (tid == 0) astore32(fme, (u32)(w + 1));
  }
}

// ---------------------------------------------------------------------------
extern "C" void kernel_launch(void* const* d_in, const int* in_sizes, int n_in,
                              void* d_out, int out_size, void* d_ws, size_t ws_size,
                              hipStream_t stream) {
  const float* x    = (const float*)d_in[0];   // [32,32,128,128]
  const float* W    = (const float*)d_in[1];   // [768,640]
  const float* bias = (const float*)d_in[2];   // [640]
  float* out = (float*)d_out;                  // [32,32,32,128]
  char* ws = (char*)d_ws;

  size_t off = 0;
  u16*   xs_h  = (u16*)(ws + off);  off += (size_t)32768 * 512 * 2;  // 33.6 MB
  u16*   xs_l  = (u16*)(ws + off);  off += (size_t)32768 * 512 * 2;  // 33.6 MB
  u16*   WxT_h = (u16*)(ws + off);  off += (size_t)640 * 512 * 2;
  u16*   WxT_l = (u16*)(ws + off);  off += (size_t)640 * 512 * 2;
  u16*   WhT_h = (u16*)(ws + off);  off += (size_t)640 * 256 * 2;
  u16*   WhT_l = (u16*)(ws + off);  off += (size_t)640 * 256 * 2;
  float* biasp = (float*)(ws + off); off += (size_t)640 * 4;
  float* Gp    = (float*)(ws + off); off += (size_t)1024 * 640 * 32 * 4; // 83.9 MB
  u64*   cbuf  = (u64*)(ws + off);  off += (size_t)1024 * 128 * 32 * 4;  // 16.8 MB
  u32*   hb    = (u32*)(ws + off);  off += (size_t)32768 * 128 * 4;      // 16.8 MB
  u32*   flags = (u32*)(ws + off);  off += 128 * 4;
  (void)ws_size;

  hipMemsetAsync(flags, 0, 128 * sizeof(u32), stream);
  k_wprep<<<dim3(640), dim3(256), 0, stream>>>(W, bias, WxT_h, WxT_l, WhT_h, WhT_l, biasp);
  k_xgather<<<dim3(8192), dim3(256), 0, stream>>>(x, xs_h, xs_l);
  k_gemm_in<<<dim3(256, 5), dim3(256), 0, stream>>>(xs_h, xs_l, WxT_h, WxT_l, biasp, Gp);
  k_rec<<<dim3(128), dim3(256), 0, stream>>>(WhT_h, WhT_l, Gp, cbuf, hb, out, flags);
}